// Round 9
// baseline (212.104 us; speedup 1.0000x reference)
//
#include <hip/hip_runtime.h>
#include <math.h>

// Problem constants
#define BB  2
#define SS  2048
#define DD  1024
#define HH  16
#define DKK 64

constexpr float kScale = 0.125f;  // 1/sqrt(64)
// p = exp(s*kScale - 16) = 2^(s*C1 - C2); exp(-16) cancels in O = sum(p*v)/sum(p)
constexpr float kC1 = 0.18033688011112042f;  // kScale * log2(e)
constexpr float kC2 = 23.0831206542234144f;  // 16 * log2(e)

typedef __bf16 bf16x8 __attribute__((ext_vector_type(8)));
typedef __bf16 bf16x4 __attribute__((ext_vector_type(4)));
typedef float f32x4 __attribute__((ext_vector_type(4)));

// Async global->LDS, 16 B per lane. LDS dest must be WAVE-UNIFORM base;
// HW scatters lane i to base + i*16.
__device__ __forceinline__ void async_copy16(const void* g, void* l) {
  __builtin_amdgcn_global_load_lds(
      (const __attribute__((address_space(1))) void*)g,
      (__attribute__((address_space(3))) void*)l, 16, 0, 0);
}

// ---------------------------------------------------------------------------
// Fused prep: blocks [0,2048) x->bf16 cvt; [2048,2560) RoPE table;
// [2560,3584) weight transpose+cvt (4 mats x 256 tile-blocks).
// ---------------------------------------------------------------------------
__global__ __launch_bounds__(256) void prep_kernel(
    const float* __restrict__ x, const int* __restrict__ pos,
    const float* __restrict__ W0, const float* __restrict__ W1,
    const float* __restrict__ W2, const float* __restrict__ W3,
    __bf16* __restrict__ xb, float2* __restrict__ rtab,
    __bf16* __restrict__ T0, __bf16* __restrict__ T1,
    __bf16* __restrict__ T2, __bf16* __restrict__ T3) {
  __shared__ __bf16 tile[64][65];
  const int bid = blockIdx.x;
  const int t = threadIdx.x;
  if (bid < 2048) {
    const size_t i = ((size_t)bid * 256 + t) * 8;
    const float4 v0 = *(const float4*)(x + i);
    const float4 v1 = *(const float4*)(x + i + 4);
    bf16x8 o;
    o[0] = (__bf16)v0.x; o[1] = (__bf16)v0.y; o[2] = (__bf16)v0.z; o[3] = (__bf16)v0.w;
    o[4] = (__bf16)v1.x; o[5] = (__bf16)v1.y; o[6] = (__bf16)v1.z; o[7] = (__bf16)v1.w;
    *(bf16x8*)(xb + i) = o;
  } else if (bid < 2560) {
    const int idx = (bid - 2048) * 256 + t;  // 131072 = 4096*32
    const int m = idx >> 5, pi = idx & 31;
    const float inv = exp2f(-0.4152410118609203f * (float)pi);
    float sn, cs;
    __sincosf((float)pos[m] * inv, &sn, &cs);
    rtab[idx] = make_float2(cs, sn);
  } else {
    const int tid2 = bid - 2560;
    const int z = tid2 >> 8, rem = tid2 & 255;
    const float* W;
    __bf16* T;
    switch (z) {
      case 0: W = W0; T = T0; break;
      case 1: W = W1; T = T1; break;
      case 2: W = W2; T = T2; break;
      default: W = W3; T = T3; break;
    }
    const int k0 = (rem >> 4) * 64, n0 = (rem & 15) * 64;
    const int c = t & 63, rg = t >> 6;
#pragma unroll
    for (int i = 0; i < 16; i++) {
      const int r = rg + i * 4;
      tile[r][c] = (__bf16)W[(size_t)(k0 + r) * DD + n0 + c];
    }
    __syncthreads();
#pragma unroll
    for (int i = 0; i < 16; i++) {
      const int r = rg + i * 4;
      T[(size_t)(n0 + r) * DD + k0 + c] = tile[c][r];
    }
  }
}

// ---------------------------------------------------------------------------
// m97-style GEMM core with XOR chunk-swizzled LDS (conflict-free B-frag reads)
// C[128,128] += A[128,K] @ Bt[128,K]^T  (K = DD = 1024)
// ---------------------------------------------------------------------------
__device__ __forceinline__ void gemm_core(
    const __bf16* __restrict__ A, const __bf16* __restrict__ Bt,
    int bm, int bn, f32x4 (&acc)[4][4], __bf16* As, __bf16* Bs) {
  const int t = threadIdx.x;
  const int lane = t & 63, wave = t >> 6;
  const int col = lane & 15, quad = lane >> 4;
  const int wm = (wave & 1) * 64, wn = (wave >> 1) * 64;
  const int r8 = lane >> 3;             // row within 8-row slab
  const int cg = (lane & 7) ^ r8;       // swizzled global chunk
  const __bf16* ag = A + (size_t)(bm + wave * 32 + r8) * DD + cg * 8;
  const __bf16* bg = Bt + (size_t)(bn + wave * 32 + r8) * DD + cg * 8;
  __bf16* asb = As + wave * 32 * 64;
  __bf16* bsb = Bs + wave * 32 * 64;

  for (int kt = 0; kt < DD; kt += 64) {
#pragma unroll
    for (int c = 0; c < 4; c++) {
      async_copy16(ag + (size_t)c * 8 * DD + kt, asb + c * 512);
      async_copy16(bg + (size_t)c * 8 * DD + kt, bsb + c * 512);
    }
    __syncthreads();
#pragma unroll
    for (int ks = 0; ks < 2; ks++) {
      bf16x8 af[4], bf[4];
#pragma unroll
      for (int i = 0; i < 4; i++)
        af[i] = *(const bf16x8*)(As + (wm + i * 16 + col) * 64 +
                                 (((ks * 4 + quad) ^ (col & 7)) * 8));
#pragma unroll
      for (int j = 0; j < 4; j++)
        bf[j] = *(const bf16x8*)(Bs + (wn + j * 16 + col) * 64 +
                                 (((ks * 4 + quad) ^ (col & 7)) * 8));
#pragma unroll
      for (int i = 0; i < 4; i++)
#pragma unroll
        for (int j = 0; j < 4; j++)
          acc[i][j] =
              __builtin_amdgcn_mfma_f32_16x16x32_bf16(af[i], bf[j], acc[i][j], 0, 0, 0);
    }
    __syncthreads();
  }
}

// ---------------------------------------------------------------------------
// Fused Q/K/V projection. grid (24, 32): blockIdx.x = mat*8 + n-tile.
// Q,K: RoPE via table, scatter [B,H,S,DK].
// V: operand-swapped MFMA (C^T = Wv^T x^T) -> written DIRECTLY in [B,H,DK,S].
// ---------------------------------------------------------------------------
__global__ __launch_bounds__(256) void qkv_gemm_kernel(
    const __bf16* __restrict__ xb, const __bf16* __restrict__ WqT,
    const __bf16* __restrict__ WkT, const __bf16* __restrict__ WvT,
    const float* __restrict__ bq, const float* __restrict__ bk,
    const float* __restrict__ bv, const float2* __restrict__ ropetab,
    __bf16* __restrict__ qo, __bf16* __restrict__ ko, __bf16* __restrict__ vo) {
  __shared__ __bf16 As[128 * 64];
  __shared__ __bf16 Bs[128 * 64];
  const int mat = blockIdx.x >> 3;
  const int bn = (blockIdx.x & 7) * 128;
  const int bm = blockIdx.y * 128;

  f32x4 acc[4][4] = {};
  const int t = threadIdx.x, lane = t & 63, wave = t >> 6;
  const int col = lane & 15, quad = lane >> 4;
  const int wm = (wave & 1) * 64, wn = (wave >> 1) * 64;

  if (mat == 2) {
    // A-operand = WvT rows (n-dim), B-operand = xb rows (m-dim)
    gemm_core(WvT, xb, bn, bm, acc, As, Bs);
    // acc[i][j][r] = Vt[n = bn+wm+i*16+quad*4+r][m = bm+wn+j*16+col]
    const int b = bm >> 11;
#pragma unroll
    for (int i = 0; i < 4; i++) {
#pragma unroll
      for (int r = 0; r < 4; r++) {
        const int n = bn + wm + i * 16 + quad * 4 + r;
        const float bb = bv[n];
        const int h = n >> 6, dk = n & 63;
        __bf16* vrow = vo + ((size_t)(b * HH + h) * DKK + dk) * SS;
#pragma unroll
        for (int j = 0; j < 4; j++) {
          const int m = bm + wn + j * 16 + col;
          vrow[m & (SS - 1)] = (__bf16)(acc[i][j][r] + bb);
        }
      }
    }
    return;
  }

  const __bf16* Bt = mat == 0 ? WqT : WkT;
  const float* bias = mat == 0 ? bq : bk;
  __bf16* out = mat == 0 ? qo : ko;
  gemm_core(xb, Bt, bm, bn, acc, As, Bs);

#pragma unroll
  for (int i = 0; i < 4; i++) {
#pragma unroll
    for (int j = 0; j < 4; j++) {
      const int n = bn + wn + j * 16 + col;
      const float bb = bias[n];
      const int pi = (n & 63) >> 1;
#pragma unroll
      for (int r = 0; r < 4; r++) {
        const int m = bm + wm + i * 16 + quad * 4 + r;
        float v = acc[i][j][r] + bb;
        {
          const float other = __shfl_xor(v, 1, 64);
          const float2 cssn = ropetab[(size_t)m * 32 + pi];
          v = (n & 1) ? (other * cssn.y + v * cssn.x)
                      : (v * cssn.x - other * cssn.y);
        }
        const int h = n >> 6, dk = n & 63;
        const int b = m >> 11, s = m & (SS - 1);
        out[((size_t)(b * HH + h) * SS + s) * DKK + dk] = (__bf16)v;
      }
    }
  }
}

// ---------------------------------------------------------------------------
// O projection: out[M,N] fp32 = ob[M,K] @ WoT[N,K]^T + bo. grid (8, 32).
// ---------------------------------------------------------------------------
__global__ __launch_bounds__(256) void oproj_gemm_kernel(
    const __bf16* __restrict__ ob, const __bf16* __restrict__ WoT,
    const float* __restrict__ bo, float* __restrict__ out) {
  __shared__ __bf16 As[128 * 64];
  __shared__ __bf16 Bs[128 * 64];
  const int bn = blockIdx.x * 128;
  const int bm = blockIdx.y * 128;
  f32x4 acc[4][4] = {};
  gemm_core(ob, WoT, bm, bn, acc, As, Bs);

  const int t = threadIdx.x, lane = t & 63, wave = t >> 6;
  const int col = lane & 15, quad = lane >> 4;
  const int wm = (wave & 1) * 64, wn = (wave >> 1) * 64;
#pragma unroll
  for (int i = 0; i < 4; i++) {
#pragma unroll
    for (int j = 0; j < 4; j++) {
      const int n = bn + wn + j * 16 + col;
      const float bb = bo[n];
#pragma unroll
      for (int r = 0; r < 4; r++) {
        const int m = bm + wm + i * 16 + quad * 4 + r;
        out[(size_t)m * DD + n] = acc[i][j][r] + bb;
      }
    }
  }
}

// ---------------------------------------------------------------------------
// Flash attention tile step. S^T orientation: QK^T computed as mfma(K, Q) so
// D rows = tokens, D cols = Q-rows. Per lane: token = quad*4+r (4 consecutive)
// -> P store packs 4 bf16 into one ds_write_b64. K/V frags hoisted once per
// tile, reused across 2 row-tiles (32 Q-rows/wave).
// kMask: apply causal mask (diagonal tile only).
// ---------------------------------------------------------------------------
template <bool kMask>
__device__ __forceinline__ void attn_tile(
    const __bf16* __restrict__ Kbuf, const __bf16* __restrict__ Vbuf,
    __bf16* __restrict__ pw, const bf16x8 (&qf)[2][2], f32x4 (&oacc)[2][4],
    float (&l_lane)[2], int tok0, int rbase_w, int col, int quad) {
  // Hoisted K fragments (shared by both row-tiles)
  bf16x8 kf[4][2];
#pragma unroll
  for (int ct = 0; ct < 4; ct++)
#pragma unroll
    for (int ks = 0; ks < 2; ks++)
      kf[ct][ks] = *(const bf16x8*)(Kbuf + (ct * 16 + col) * 64 +
                                    (((ks * 4 + quad) ^ (col & 7)) * 8));
#pragma unroll
  for (int rt = 0; rt < 2; rt++) {
    f32x4 sc[4] = {};
#pragma unroll
    for (int ct = 0; ct < 4; ct++)
#pragma unroll
      for (int ks = 0; ks < 2; ks++)
        sc[ct] = __builtin_amdgcn_mfma_f32_16x16x32_bf16(kf[ct][ks],
                                                         qf[rt][ks], sc[ct],
                                                         0, 0, 0);
    const int rg = rbase_w + rt * 16 + col;  // this lane's Q-row
#pragma unroll
    for (int ct = 0; ct < 4; ct++) {
      bf16x4 pk;
#pragma unroll
      for (int r = 0; r < 4; r++) {
        float p = exp2f(sc[ct][r] * kC1 - kC2);
        if (kMask && (tok0 + ct * 16 + quad * 4 + r) > rg) p = 0.0f;
        l_lane[rt] += p;
        pk[r] = (__bf16)p;
      }
      *(bf16x4*)(pw + (rt * 16 + col) * 72 + ct * 16 + quad * 4) = pk;
    }
  }
  // Hoisted V fragments (shared by both row-tiles)
  bf16x8 vf[4][2];
#pragma unroll
  for (int dt = 0; dt < 4; dt++)
#pragma unroll
    for (int ks = 0; ks < 2; ks++)
      vf[dt][ks] = *(const bf16x8*)(Vbuf + (dt * 16 + col) * 64 +
                                    (((ks * 4 + quad) ^ (col & 7)) * 8));
#pragma unroll
  for (int rt = 0; rt < 2; rt++) {
    bf16x8 pf[2];
#pragma unroll
    for (int ks = 0; ks < 2; ks++)
      pf[ks] =
          *(const bf16x8*)(pw + (rt * 16 + col) * 72 + ks * 32 + quad * 8);
#pragma unroll
    for (int dt = 0; dt < 4; dt++)
#pragma unroll
      for (int ks = 0; ks < 2; ks++)
        oacc[rt][dt] = __builtin_amdgcn_mfma_f32_16x16x32_bf16(
            pf[ks], vf[dt][ks], oacc[rt][dt], 0, 0, 0);
  }
}

// ---------------------------------------------------------------------------
// MFMA flash attention: 128-row Q-tiles, 32 rows/wave, paired balanced grid
// (pairs pr & 15-pr -> 34 staged 64-token tiles per block, 256 blocks = 1/CU),
// K/V double-buffered with prefetch (1 barrier/iter), fixed-max softmax,
// S^T QK orientation with packed P stores, diag peeling + empty-wave skip.
// q,k in [B,H,S,DK]; vt in [B,H,DK,S]; o out [B,S,H,DK] bf16.
// ---------------------------------------------------------------------------
__global__ __launch_bounds__(256) void flash_attn_mfma_kernel(
    const __bf16* __restrict__ q, const __bf16* __restrict__ k,
    const __bf16* __restrict__ vt, __bf16* __restrict__ o) {
  __shared__ __bf16 Ks[2][64 * 64];    // [token][dk], chunk-swizzled
  __shared__ __bf16 Vs[2][64 * 64];    // [d][token], chunk-swizzled
  __shared__ __bf16 Ps[4][32 * 72];    // per-wave [qrow][token], stride 72

  const int bh = blockIdx.x;   // 0..31
  const int pr = blockIdx.y;   // 0..7
  const int t = threadIdx.x, lane = t & 63, wave = t >> 6;
  const int col = lane & 15, quad = lane >> 4;
  const int r8 = lane >> 3;            // row in 8-row slab
  const int cg = (lane & 7) ^ r8;      // swizzled global chunk

  const __bf16* qb = q + (size_t)bh * SS * DKK;
  const __bf16* kb = k + (size_t)bh * SS * DKK;
  const __bf16* vtb = vt + (size_t)bh * DKK * SS;
  const int b = bh / HH, h = bh % HH;
  __bf16* pw = (__bf16*)Ps[wave];

#pragma unroll
  for (int phase = 0; phase < 2; phase++) {
    const int qt = phase == 0 ? pr : (15 - pr);  // 128-row tile index
    const int rbase_w = qt * 128 + wave * 32;    // wave's first Q-row

    // Q fragments: 2 row-tiles x 2 k-halves (held in registers)
    bf16x8 qf[2][2];
#pragma unroll
    for (int rt = 0; rt < 2; rt++)
#pragma unroll
      for (int ks = 0; ks < 2; ks++)
        qf[rt][ks] = *(const bf16x8*)(qb +
                                      (size_t)(rbase_w + rt * 16 + col) * DKK +
                                      ks * 32 + quad * 8);

    f32x4 oacc[2][4] = {};
    float l_lane[2] = {0.f, 0.f};

    const int nkt = 2 * qt + 2;  // staged 64-token tiles

    // Prologue: stage tile 0 into buffer 0
#pragma unroll
    for (int i = 0; i < 2; i++) {
      const int slab = wave * 2 + i;
      async_copy16(kb + (size_t)(slab * 8 + r8) * DKK + cg * 8,
                   Ks[0] + slab * 512);
      async_copy16(vtb + (size_t)(slab * 8 + r8) * SS + cg * 8,
                   Vs[0] + slab * 512);
    }

    for (int kt = 0; kt < nkt; kt++) {
      const int cur = kt & 1;
      __syncthreads();  // drains stage(kt); protects buffer reuse

      if (kt + 1 < nkt) {  // prefetch next tile into other buffer
#pragma unroll
        for (int i = 0; i < 2; i++) {
          const int slab = wave * 2 + i;
          async_copy16(
              kb + (size_t)((kt + 1) * 64 + slab * 8 + r8) * DKK + cg * 8,
              Ks[cur ^ 1] + slab * 512);
          async_copy16(
              vtb + (size_t)(slab * 8 + r8) * SS + (kt + 1) * 64 + cg * 8,
              Vs[cur ^ 1] + slab * 512);
        }
      }

      const int tok0 = kt * 64;
      if (tok0 <= rbase_w + 31) {          // not fully above the diagonal
        if (tok0 + 63 <= rbase_w)          // fully unmasked
          attn_tile<false>(Ks[cur], Vs[cur], pw, qf, oacc, l_lane, tok0,
                           rbase_w, col, quad);
        else                               // diagonal tile
          attn_tile<true>(Ks[cur], Vs[cur], pw, qf, oacc, l_lane, tok0,
                          rbase_w, col, quad);
      }
    }
    __syncthreads();  // protect buffers before next phase's prologue staging

    // Phase epilogue: reduce l across quads (l lives at lane col = qrow),
    // redistribute to D-layout rows via shfl, normalize, write o [B,S,H,DK].
#pragma unroll
    for (int rt = 0; rt < 2; rt++) {
      float l = l_lane[rt];
      l += __shfl_xor(l, 16, 64);
      l += __shfl_xor(l, 32, 64);
#pragma unroll
      for (int r = 0; r < 4; r++) {
        const float lr = __shfl(l, quad * 4 + r, 64);
        const float inv_l = 1.0f / lr;
        const int s = rbase_w + rt * 16 + quad * 4 + r;
#pragma unroll
        for (int dt = 0; dt < 4; dt++)
          o[((size_t)(b * SS + s) * HH + h) * DKK + dt * 16 + col] =
              (__bf16)(oacc[rt][dt][r] * inv_l);
      }
    }
  }
}

// ---------------------------------------------------------------------------
extern "C" void kernel_launch(void* const* d_in, const int* in_sizes, int n_in,
                              void* d_out, int out_size, void* d_ws,
                              size_t ws_size, hipStream_t stream) {
  const float* x  = (const float*)d_in[0];
  const int*  pos = (const int*)d_in[1];
  const float* Wq = (const float*)d_in[2];
  const float* bq = (const float*)d_in[3];
  const float* Wk = (const float*)d_in[4];
  const float* bk = (const float*)d_in[5];
  const float* Wv = (const float*)d_in[6];
  const float* bv = (const float*)d_in[7];
  const float* Wo = (const float*)d_in[8];
  const float* bo = (const float*)d_in[9];
  float* out = (float*)d_out;

  char* ws = (char*)d_ws;
  __bf16* xb  = (__bf16*)(ws);                          // 8 MB
  __bf16* WqT = (__bf16*)(ws + ((size_t)8  << 20));     // 2 MB each
  __bf16* WkT = (__bf16*)(ws + ((size_t)10 << 20));
  __bf16* WvT = (__bf16*)(ws + ((size_t)12 << 20));
  __bf16* WoT = (__bf16*)(ws + ((size_t)14 << 20));
  __bf16* qb  = (__bf16*)(ws + ((size_t)16 << 20));     // 8 MB each
  __bf16* kb  = (__bf16*)(ws + ((size_t)24 << 20));
  __bf16* vtb = (__bf16*)(ws + ((size_t)32 << 20));     // V, transposed layout
  __bf16* ob  = (__bf16*)(ws + ((size_t)40 << 20));
  float2* rtab = (float2*)(ws + ((size_t)48 << 20));    // 1 MB; total 49 MB

  prep_kernel<<<3584, 256, 0, stream>>>(x, pos, Wq, Wk, Wv, Wo, xb, rtab, WqT,
                                        WkT, WvT, WoT);
  qkv_gemm_kernel<<<dim3(24, 32), 256, 0, stream>>>(xb, WqT, WkT, WvT, bq, bk,
                                                    bv, rtab, qb, kb, vtb);
  flash_attn_mfma_kernel<<<dim3(32, 8), 256, 0, stream>>>(qb, kb, vtb, ob);
  oproj_gemm_kernel<<<dim3(8, 32), 256, 0, stream>>>(ob, WoT, bo, out);
}